// Round 1
// baseline (1337.655 us; speedup 1.0000x reference)
//
#include <hip/hip_runtime.h>
#include <math.h>

// Problem constants
#define B_     32
#define F_     64
#define T_     518
#define HID    64
#define GATES  256   // 4*HID
#define CCH    128   // 2*HID lstm output channels
#define NWAVE  6
#define WCH    768   // NWAVE*CCH
#define L2_    516   // T-2   (conv2 out)
#define L3_    512   // L2-4  (conv3 out)
#define L4_    510   // L3-2  (conv4/conv5 out)

// ---------------------------------------------------------------------------
// K1: xg[b,t,g] = sum_f x[b,f,t]*wih[g,f] + bias[g]  (both directions)
// grid(65, 32), block 256
__global__ void xg_kernel(const float* __restrict__ x,
                          const float* __restrict__ wif, const float* __restrict__ bf,
                          const float* __restrict__ wir, const float* __restrict__ br,
                          float* __restrict__ xg_f, float* __restrict__ xg_r) {
    const int g  = threadIdx.x;
    const int b  = blockIdx.y;
    const int t0 = blockIdx.x * 8;
    float4 wa[16], wb[16];
    const float4* w0 = (const float4*)(wif + g * F_);
    const float4* w1 = (const float4*)(wir + g * F_);
#pragma unroll
    for (int i = 0; i < 16; ++i) { wa[i] = w0[i]; wb[i] = w1[i]; }
    const float bfv = bf[g], brv = br[g];
    for (int tt = 0; tt < 8; ++tt) {
        const int t = t0 + tt;
        if (t >= T_) break;
        const float* xp = x + (size_t)b * F_ * T_ + t;
        float a0 = bfv, a1 = brv;
#pragma unroll
        for (int i = 0; i < 16; ++i) {
            float x0 = xp[(i * 4 + 0) * T_];
            float x1 = xp[(i * 4 + 1) * T_];
            float x2 = xp[(i * 4 + 2) * T_];
            float x3 = xp[(i * 4 + 3) * T_];
            a0 += wa[i].x * x0 + wa[i].y * x1 + wa[i].z * x2 + wa[i].w * x3;
            a1 += wb[i].x * x0 + wb[i].y * x1 + wb[i].z * x2 + wb[i].w * x3;
        }
        const size_t o = ((size_t)b * T_ + t) * GATES + g;
        xg_f[o] = a0;
        xg_r[o] = a1;
    }
}

// ---------------------------------------------------------------------------
// K2: LSTM recurrence. grid(64) = 32 batches x 2 dirs, block 256 (one gate row each)
__global__ __launch_bounds__(256) void lstm_kernel(
        const float* __restrict__ xg_f, const float* __restrict__ xg_r,
        const float* __restrict__ whf, const float* __restrict__ whr,
        float* __restrict__ X) {
    const int dir = blockIdx.x & 1;
    const int b   = blockIdx.x >> 1;
    const float* xg  = dir ? xg_r : xg_f;
    const float* whh = dir ? whr : whf;
    const int r = threadIdx.x;
    float4 w[16];
    const float4* wp = (const float4*)(whh + r * HID);
#pragma unroll
    for (int i = 0; i < 16; ++i) w[i] = wp[i];
    __shared__ __align__(16) float hs[HID];
    __shared__ float gbuf[GATES];
    float c = 0.f;
    if (r < HID) hs[r] = 0.f;
    __syncthreads();
    const float* xgb = xg + (size_t)b * T_ * GATES;
    float* Xrow = X + ((size_t)(b * CCH + dir * HID + r)) * T_;  // valid for r<64
    for (int s = 0; s < T_; ++s) {
        const int t = dir ? (T_ - 1 - s) : s;
        float acc = xgb[(size_t)t * GATES + r];
#pragma unroll
        for (int i = 0; i < 16; ++i) {
            float4 h4 = ((const float4*)hs)[i];
            acc += w[i].x * h4.x + w[i].y * h4.y + w[i].z * h4.z + w[i].w * h4.w;
        }
        gbuf[r] = acc;
        __syncthreads();
        if (r < HID) {
            float ig = gbuf[r], fg = gbuf[HID + r], gg = gbuf[2 * HID + r], og = gbuf[3 * HID + r];
            float si = 1.f / (1.f + __expf(-ig));
            float sf = 1.f / (1.f + __expf(-fg));
            float so = 1.f / (1.f + __expf(-og));
            c = sf * c + si * tanhf(gg);
            float h = so * tanhf(c);
            hs[r] = h;
            Xrow[t] = h;
        }
        __syncthreads();
    }
}

// ---------------------------------------------------------------------------
// K3: wave module. grid(ceil(T/256)=3, 128, 32), block 256
__global__ void wave_kernel(const float* __restrict__ X,
                            const float* __restrict__ bw, const float* __restrict__ bb,
                            float* __restrict__ wave) {
    const int b = blockIdx.z, c = blockIdx.y;
    const int t0 = blockIdx.x * 256;
    const int tid = threadIdx.x;
    __shared__ float xs[256 + 14];
    __shared__ float bws[NWAVE][16];
    __shared__ float bbs[NWAVE];
    const float* xrow = X + ((size_t)(b * CCH + c)) * T_;
    for (int i = tid; i < 270; i += 256) {
        int tt = t0 - 7 + i;
        xs[i] = (tt >= 0 && tt < T_) ? xrow[tt] : 0.f;
    }
    if (tid < NWAVE * 15) bws[tid / 15][tid % 15] = bw[tid];
    if (tid < NWAVE) bbs[tid] = bb[tid];
    __syncthreads();
    const int t = t0 + tid;
    if (t >= T_) return;
    float win[15];
#pragma unroll
    for (int k = 0; k < 15; ++k) win[k] = xs[tid + k];
    float e[8];
    e[0] = win[7];
#pragma unroll
    for (int m = 1; m < 8; ++m) e[m] = win[7 - m] + win[7 + m];
    const float c0 = 6.28318530717958647692f / 15.f;  // 2*pi/WIDE
#pragma unroll
    for (int ii = 0; ii < NWAVE; ++ii) {
        float sc = bbs[ii];
#pragma unroll
        for (int k = 0; k < 15; ++k) sc += win[k] * bws[ii][k];
        sc = fmaxf(sc, 0.f);
        const float phi = c0 * (float)(ii + 1) * sc;
        float o = e[0];
#pragma unroll
        for (int m = 1; m < 8; ++m) o += e[m] * __cosf(phi * (float)m);
        const float q = (truncf(sc * 15.f) + 1.f) * (2.f / 17.f);
        wave[((size_t)(b * WCH + ii * CCH + c)) * T_ + t] = o * rsqrtf(q);
    }
}

// ---------------------------------------------------------------------------
// Generic training-mode BN statistics: one block per channel
__global__ void bn_stats_kernel(const float* __restrict__ x, int Bn, int C, int L,
                                float* __restrict__ mean, float* __restrict__ rstd) {
    const int c = blockIdx.x;
    const int tid = threadIdx.x;
    float s = 0.f, s2 = 0.f;
    for (int b = 0; b < Bn; ++b) {
        const float* row = x + ((size_t)b * C + c) * L;
        for (int l = tid; l < L; l += 256) { float v = row[l]; s += v; s2 += v * v; }
    }
#pragma unroll
    for (int off = 32; off > 0; off >>= 1) { s += __shfl_down(s, off); s2 += __shfl_down(s2, off); }
    __shared__ float ss[4], ss2[4];
    if ((tid & 63) == 0) { ss[tid >> 6] = s; ss2[tid >> 6] = s2; }
    __syncthreads();
    if (tid == 0) {
        float S = ss[0] + ss[1] + ss[2] + ss[3];
        float S2 = ss2[0] + ss2[1] + ss2[2] + ss2[3];
        float n = (float)(Bn * L);
        float m = S / n;
        float v = S2 / n - m * m;
        mean[c] = m;
        rstd[c] = rsqrtf(v + 1e-5f);
    }
}

// In-place BN affine apply
__global__ void bn_apply_kernel(float* __restrict__ x, const float* __restrict__ mean,
                                const float* __restrict__ rstd, const float* __restrict__ g,
                                const float* __restrict__ be, int C, int L, int total) {
    int i = blockIdx.x * 256 + threadIdx.x;
    if (i >= total) return;
    int c = (i / L) % C;
    x[i] = (x[i] - mean[c]) * rstd[c] * g[c] + be[c];
}

// ---------------------------------------------------------------------------
// conv2: [32,768,518] -> relu -> [32,128,516], k=3. grid(3,16,32), block 256
__global__ void conv2_kernel(const float* __restrict__ in, const float* __restrict__ w,
                             const float* __restrict__ bias, float* __restrict__ out) {
    const int t = blockIdx.x * 256 + threadIdx.x;
    const int o0 = blockIdx.y * 8;
    const int b = blockIdx.z;
    if (t >= L2_) return;
    float acc[8];
#pragma unroll
    for (int j = 0; j < 8; ++j) acc[j] = bias[o0 + j];
    const float* inb = in + (size_t)b * WCH * T_ + t;
    const float* wb = w + (size_t)o0 * WCH * 3;
    for (int c = 0; c < WCH; ++c) {
        float x0 = inb[c * T_], x1 = inb[c * T_ + 1], x2 = inb[c * T_ + 2];
        const float* wc = wb + c * 3;
#pragma unroll
        for (int j = 0; j < 8; ++j) {
            const float* wj = wc + (size_t)j * WCH * 3;
            acc[j] += x0 * wj[0] + x1 * wj[1] + x2 * wj[2];
        }
    }
    const size_t ob = ((size_t)b * 128 + o0) * L2_ + t;
#pragma unroll
    for (int j = 0; j < 8; ++j) out[ob + (size_t)j * L2_] = fmaxf(acc[j], 0.f);
}

// conv3: [32,128,516] -> relu -> [32,32,512], k=5. grid(2,4,32), block 256
__global__ void conv3_kernel(const float* __restrict__ in, const float* __restrict__ w,
                             const float* __restrict__ bias, float* __restrict__ out) {
    const int t = blockIdx.x * 256 + threadIdx.x;
    const int o0 = blockIdx.y * 8;
    const int b = blockIdx.z;
    if (t >= L3_) return;
    float acc[8];
#pragma unroll
    for (int j = 0; j < 8; ++j) acc[j] = bias[o0 + j];
    const float* inb = in + (size_t)b * 128 * L2_ + t;
    const float* wb = w + (size_t)o0 * 128 * 5;
    for (int c = 0; c < 128; ++c) {
        float x0 = inb[c * L2_], x1 = inb[c * L2_ + 1], x2 = inb[c * L2_ + 2];
        float x3 = inb[c * L2_ + 3], x4 = inb[c * L2_ + 4];
        const float* wc = wb + c * 5;
#pragma unroll
        for (int j = 0; j < 8; ++j) {
            const float* wj = wc + (size_t)j * 128 * 5;
            acc[j] += x0 * wj[0] + x1 * wj[1] + x2 * wj[2] + x3 * wj[3] + x4 * wj[4];
        }
    }
    const size_t ob = ((size_t)b * 32 + o0) * L3_ + t;
#pragma unroll
    for (int j = 0; j < 8; ++j) out[ob + (size_t)j * L3_] = fmaxf(acc[j], 0.f);
}

// conv4: [32,32,512] -> relu -> [32,16,510], k=3. grid(2,16,32), block 256
__global__ void conv4_kernel(const float* __restrict__ in, const float* __restrict__ w,
                             const float* __restrict__ bias, float* __restrict__ out) {
    const int t = blockIdx.x * 256 + threadIdx.x;
    const int o = blockIdx.y;
    const int b = blockIdx.z;
    if (t >= L4_) return;
    float acc = bias[o];
    const float* inb = in + (size_t)b * 32 * L3_ + t;
    const float* wo = w + (size_t)o * 32 * 3;
    for (int c = 0; c < 32; ++c) {
        acc += inb[c * L3_] * wo[c * 3] + inb[c * L3_ + 1] * wo[c * 3 + 1] +
               inb[c * L3_ + 2] * wo[c * 3 + 2];
    }
    out[((size_t)b * 16 + o) * L4_ + t] = fmaxf(acc, 0.f);
}

// DWT branch: channel-mean then Haar cascade bands, upsampled. grid(32), block 512
__global__ void dwt_kernel(const float* __restrict__ y3, float* __restrict__ dwt) {
    const int b = blockIdx.x, l = threadIdx.x;  // l in [0,512)
    __shared__ float cm[L3_];
    float s = 0.f;
    for (int ch = 0; ch < 32; ++ch) s += y3[((size_t)b * 32 + ch) * L3_ + l];
    cm[l] = s * (1.f / 32.f);
    __syncthreads();
    const float s1 = 0.70710678118654752440f;
    const float s2 = 0.5f;
    const float s3 = 0.35355339059327378f;
    const float s4 = 0.25f;
    const int b16 = l & ~15, b8 = l & ~7, b4v = l & ~3, b2v = l & ~1;
    float sa = 0.f, sb = 0.f;
#pragma unroll
    for (int i = 0; i < 8; ++i) { sa += cm[b16 + i]; sb += cm[b16 + 8 + i]; }
    float a4 = (sa + sb) * s4;
    float d4 = (sa - sb) * s4;
    float ta = 0.f, tb = 0.f;
#pragma unroll
    for (int i = 0; i < 4; ++i) { ta += cm[b8 + i]; tb += cm[b8 + 4 + i]; }
    float d3 = (ta - tb) * s3;
    float d2 = (cm[b4v] + cm[b4v + 1] - cm[b4v + 2] - cm[b4v + 3]) * s2;
    float d1 = (cm[b2v] - cm[b2v + 1]) * s1;
    const size_t base = (size_t)b * 5 * L3_ + l;
    dwt[base] = a4;
    dwt[base + L3_] = d4;
    dwt[base + 2 * L3_] = d3;
    dwt[base + 3 * L3_] = d2;
    dwt[base + 4 * L3_] = d1;
}

// conv5: [32,5,512] -> relu -> [32,16,510], k=3. grid(2,16,32), block 256
__global__ void conv5_kernel(const float* __restrict__ in, const float* __restrict__ w,
                             const float* __restrict__ bias, float* __restrict__ out) {
    const int t = blockIdx.x * 256 + threadIdx.x;
    const int o = blockIdx.y;
    const int b = blockIdx.z;
    if (t >= L4_) return;
    float acc = bias[o];
    const float* inb = in + (size_t)b * 5 * L3_ + t;
    const float* wo = w + (size_t)o * 5 * 3;
#pragma unroll
    for (int c = 0; c < 5; ++c) {
        acc += inb[c * L3_] * wo[c * 3] + inb[c * L3_ + 1] * wo[c * 3 + 1] +
               inb[c * L3_ + 2] * wo[c * 3 + 2];
    }
    out[((size_t)b * 16 + o) * L4_ + t] = fmaxf(acc, 0.f);
}

// Final: fold BN4/BN5 into pooling (mean of affine = affine of mean), then FC.
// grid(32), block 256
__global__ void final_kernel(const float* __restrict__ y4, const float* __restrict__ y5,
                             const float* __restrict__ m4, const float* __restrict__ r4,
                             const float* __restrict__ g4, const float* __restrict__ be4,
                             const float* __restrict__ m5, const float* __restrict__ r5,
                             const float* __restrict__ g5, const float* __restrict__ be5,
                             const float* __restrict__ fcw, const float* __restrict__ fcb,
                             float* __restrict__ out) {
    const int b = blockIdx.x;
    const int tid = threadIdx.x;
    const int ch = tid >> 4, lane = tid & 15;
    float s4 = 0.f, s5 = 0.f;
    const float* p4 = y4 + ((size_t)b * 16 + ch) * L4_;
    const float* p5 = y5 + ((size_t)b * 16 + ch) * L4_;
    for (int l = lane; l < L4_; l += 16) { s4 += p4[l]; s5 += p5[l]; }
#pragma unroll
    for (int off = 8; off > 0; off >>= 1) { s4 += __shfl_down(s4, off); s5 += __shfl_down(s5, off); }
    __shared__ float shmean[16];
    if (lane == 0) {
        float mm4 = s4 / (float)L4_, mm5 = s5 / (float)L4_;
        float v4 = (mm4 - m4[ch]) * r4[ch] * g4[ch] + be4[ch];
        float v5 = (mm5 - m5[ch]) * r5[ch] * g5[ch] + be5[ch];
        shmean[ch] = 0.5f * (v4 + v5);
    }
    __syncthreads();
    if (tid < 10) {
        float a = fcb[tid];
#pragma unroll
        for (int c = 0; c < 16; ++c) a += shmean[c] * fcw[tid * 16 + c];
        out[b * 10 + tid] = a;
    }
}

// ---------------------------------------------------------------------------
extern "C" void kernel_launch(void* const* d_in, const int* in_sizes, int n_in,
                              void* d_out, int out_size, void* d_ws, size_t ws_size,
                              hipStream_t stream) {
    (void)in_sizes; (void)n_in; (void)out_size; (void)ws_size;
    const float* x   = (const float*)d_in[0];
    const float* wif = (const float*)d_in[1];
    const float* whf = (const float*)d_in[2];
    const float* bf  = (const float*)d_in[3];
    const float* wir = (const float*)d_in[4];
    const float* whr = (const float*)d_in[5];
    const float* br  = (const float*)d_in[6];
    const float* bw  = (const float*)d_in[7];
    const float* bb  = (const float*)d_in[8];
    const float* g1  = (const float*)d_in[9];  const float* be1 = (const float*)d_in[10];
    const float* g2  = (const float*)d_in[11]; const float* be2 = (const float*)d_in[12];
    const float* g3  = (const float*)d_in[13]; const float* be3 = (const float*)d_in[14];
    const float* g4  = (const float*)d_in[15]; const float* be4 = (const float*)d_in[16];
    const float* g5  = (const float*)d_in[17]; const float* be5 = (const float*)d_in[18];
    const float* w2  = (const float*)d_in[19]; const float* b2  = (const float*)d_in[20];
    const float* w3  = (const float*)d_in[21]; const float* b3  = (const float*)d_in[22];
    const float* w4  = (const float*)d_in[23]; const float* b4  = (const float*)d_in[24];
    const float* w5  = (const float*)d_in[25]; const float* b5  = (const float*)d_in[26];
    const float* fcw = (const float*)d_in[27]; const float* fcb = (const float*)d_in[28];
    float* out = (float*)d_out;
    float* ws  = (float*)d_ws;

    // Workspace layout (floats). xg region is reused by `wave` after the LSTM.
    float* xg_f = ws;                       //  4,243,456
    float* xg_r = ws + 4243456;             //  4,243,456
    float* wave = ws;                       // 12,730,368 (reuses xg region)
    float* X    = ws + 12730368;            //  2,121,728
    float* y2   = ws + 14852096;            //  2,113,536
    float* y3   = ws + 16965632;            //    524,288
    float* y4   = ws + 17489920;            //    261,120
    float* y5   = ws + 17751040;            //    261,120
    float* dwt  = ws + 18012160;            //     81,920
    float* m1 = ws + 18094080; float* r1 = m1 + 768;
    float* m2 = r1 + 768;      float* r2 = m2 + 128;
    float* m3 = r2 + 128;      float* r3 = m3 + 32;
    float* m4 = r3 + 32;       float* r4 = m4 + 16;
    float* m5 = r4 + 16;       float* r5 = m5 + 16;   // ends at 18,096,000 floats (~72.4 MB)

    // 1) input projections (both directions)
    xg_kernel<<<dim3(65, 32), 256, 0, stream>>>(x, wif, bf, wir, br, xg_f, xg_r);
    // 2) bidirectional LSTM recurrence -> X [32,128,518]
    lstm_kernel<<<dim3(64), 256, 0, stream>>>(xg_f, xg_r, whf, whr, X);
    // 3) wave module -> wave [32,768,518]
    wave_kernel<<<dim3(3, CCH, B_), 256, 0, stream>>>(X, bw, bb, wave);
    // 4) BN1
    bn_stats_kernel<<<dim3(WCH), 256, 0, stream>>>(wave, B_, WCH, T_, m1, r1);
    bn_apply_kernel<<<dim3((B_ * WCH * T_ + 255) / 256), 256, 0, stream>>>(
        wave, m1, r1, g1, be1, WCH, T_, B_ * WCH * T_);
    // 5) conv2 + relu -> y2; BN2
    conv2_kernel<<<dim3(3, 16, B_), 256, 0, stream>>>(wave, w2, b2, y2);
    bn_stats_kernel<<<dim3(128), 256, 0, stream>>>(y2, B_, 128, L2_, m2, r2);
    bn_apply_kernel<<<dim3((B_ * 128 * L2_ + 255) / 256), 256, 0, stream>>>(
        y2, m2, r2, g2, be2, 128, L2_, B_ * 128 * L2_);
    // 6) conv3 + relu -> y3; BN3
    conv3_kernel<<<dim3(2, 4, B_), 256, 0, stream>>>(y2, w3, b3, y3);
    bn_stats_kernel<<<dim3(32), 256, 0, stream>>>(y3, B_, 32, L3_, m3, r3);
    bn_apply_kernel<<<dim3((B_ * 32 * L3_ + 255) / 256), 256, 0, stream>>>(
        y3, m3, r3, g3, be3, 32, L3_, B_ * 32 * L3_);
    // 7) conv4 + relu -> y4; BN4 stats only (apply folded into final)
    conv4_kernel<<<dim3(2, 16, B_), 256, 0, stream>>>(y3, w4, b4, y4);
    bn_stats_kernel<<<dim3(16), 256, 0, stream>>>(y4, B_, 16, L4_, m4, r4);
    // 8) DWT bands from y3 -> dwt [32,5,512]; conv5 + relu -> y5; BN5 stats
    dwt_kernel<<<dim3(B_), 512, 0, stream>>>(y3, dwt);
    conv5_kernel<<<dim3(2, 16, B_), 256, 0, stream>>>(dwt, w5, b5, y5);
    bn_stats_kernel<<<dim3(16), 256, 0, stream>>>(y5, B_, 16, L4_, m5, r5);
    // 9) pool (+BN4/BN5 affine) + FC -> out [32,10]
    final_kernel<<<dim3(B_), 256, 0, stream>>>(y4, y5, m4, r4, g4, be4, m5, r5, g5, be5,
                                               fcw, fcb, out);
}

// Round 2
// 1161.714 us; speedup vs baseline: 1.1514x; 1.1514x over previous
//
#include <hip/hip_runtime.h>
#include <math.h>

// Problem constants
#define B_     32
#define F_     64
#define T_     518
#define HID    64
#define GATES  256   // 4*HID
#define CCH    128   // 2*HID lstm output channels
#define NWAVE  6
#define WCH    768   // NWAVE*CCH
#define L2_    516   // T-2   (conv2 out)
#define L3_    512   // L2-4  (conv3 out)
#define L4_    510   // L3-2  (conv4/conv5 out)

__device__ __forceinline__ float frcp(float x) { return __builtin_amdgcn_rcpf(x); }
__device__ __forceinline__ float fsigmoid(float x) { return frcp(1.f + __expf(-x)); }
__device__ __forceinline__ float ftanh(float x) { return 1.f - 2.f * frcp(1.f + __expf(2.f * x)); }

// ---------------------------------------------------------------------------
// K1: xg[b,t,g] = sum_f x[b,f,t]*wih[g,f] + bias[g]  (both directions)
// grid(65, 32), block 256
__global__ void xg_kernel(const float* __restrict__ x,
                          const float* __restrict__ wif, const float* __restrict__ bf,
                          const float* __restrict__ wir, const float* __restrict__ br,
                          float* __restrict__ xg_f, float* __restrict__ xg_r) {
    const int g  = threadIdx.x;
    const int b  = blockIdx.y;
    const int t0 = blockIdx.x * 8;
    float4 wa[16], wb[16];
    const float4* w0 = (const float4*)(wif + g * F_);
    const float4* w1 = (const float4*)(wir + g * F_);
#pragma unroll
    for (int i = 0; i < 16; ++i) { wa[i] = w0[i]; wb[i] = w1[i]; }
    const float bfv = bf[g], brv = br[g];
    for (int tt = 0; tt < 8; ++tt) {
        const int t = t0 + tt;
        if (t >= T_) break;
        const float* xp = x + (size_t)b * F_ * T_ + t;
        float a0 = bfv, a1 = brv;
#pragma unroll
        for (int i = 0; i < 16; ++i) {
            float x0 = xp[(i * 4 + 0) * T_];
            float x1 = xp[(i * 4 + 1) * T_];
            float x2 = xp[(i * 4 + 2) * T_];
            float x3 = xp[(i * 4 + 3) * T_];
            a0 += wa[i].x * x0 + wa[i].y * x1 + wa[i].z * x2 + wa[i].w * x3;
            a1 += wb[i].x * x0 + wb[i].y * x1 + wb[i].z * x2 + wb[i].w * x3;
        }
        const size_t o = ((size_t)b * T_ + t) * GATES + g;
        xg_f[o] = a0;
        xg_r[o] = a1;
    }
}

// ---------------------------------------------------------------------------
// K2: LSTM recurrence — one WAVE per (b,dir). Lane r owns h_r,c_r in registers
// and computes all 4 gate dot products (weights resident in 256 VGPRs).
// No s_barrier anywhere: single-wave block, LDS h-broadcast ordered by the
// in-order DS pipe + explicit lgkmcnt waits. Global xg prefetch stays in
// flight across steps (no vmcnt drain).
// grid(64), block 64
__global__ __launch_bounds__(64, 1) void lstm_kernel(
        const float* __restrict__ xg_f, const float* __restrict__ xg_r,
        const float* __restrict__ whf, const float* __restrict__ whr,
        float* __restrict__ X) {
    const int dir = blockIdx.x & 1;
    const int b   = blockIdx.x >> 1;
    const float* xg  = (dir ? xg_r : xg_f) + (size_t)b * T_ * GATES;
    const float* whh = dir ? whr : whf;
    const int r = threadIdx.x;  // 0..63, owns h[r], c[r]

    float4 wi[16], wf4[16], wg4[16], wo4[16];
    {
        const float4* pi = (const float4*)(whh + (size_t)r * HID);
        const float4* pf = (const float4*)(whh + (size_t)(HID + r) * HID);
        const float4* pg = (const float4*)(whh + (size_t)(2 * HID + r) * HID);
        const float4* po = (const float4*)(whh + (size_t)(3 * HID + r) * HID);
#pragma unroll
        for (int i = 0; i < 16; ++i) { wi[i] = pi[i]; wf4[i] = pf[i]; wg4[i] = pg[i]; wo4[i] = po[i]; }
    }

    __shared__ __align__(16) float hs[HID];
    hs[r] = 0.f;
    float c = 0.f;
    float* Xrow = X + ((size_t)(b * CCH + dir * HID + r)) * T_;

    int t = dir ? (T_ - 1) : 0;
    const int step = dir ? -1 : 1;
    // prefetch first step's gate pre-activations
    float xi = xg[(size_t)t * GATES + r];
    float xf = xg[(size_t)t * GATES + HID + r];
    float xgg = xg[(size_t)t * GATES + 2 * HID + r];
    float xo = xg[(size_t)t * GATES + 3 * HID + r];
    asm volatile("s_waitcnt lgkmcnt(0)" ::: "memory");  // hs init visible

    for (int s = 0; s < T_; ++s) {
        // gate dot products: broadcast-read h from LDS (conflict-free), FMA into
        // 4 independent float4 chains per gate.
        float4 ai = {0.f, 0.f, 0.f, 0.f}, af = ai, ag = ai, ao = ai;
#pragma unroll
        for (int i = 0; i < 16; ++i) {
            float4 h4 = ((const float4*)hs)[i];
            ai.x = fmaf(wi[i].x, h4.x, ai.x);  ai.y = fmaf(wi[i].y, h4.y, ai.y);
            ai.z = fmaf(wi[i].z, h4.z, ai.z);  ai.w = fmaf(wi[i].w, h4.w, ai.w);
            af.x = fmaf(wf4[i].x, h4.x, af.x); af.y = fmaf(wf4[i].y, h4.y, af.y);
            af.z = fmaf(wf4[i].z, h4.z, af.z); af.w = fmaf(wf4[i].w, h4.w, af.w);
            ag.x = fmaf(wg4[i].x, h4.x, ag.x); ag.y = fmaf(wg4[i].y, h4.y, ag.y);
            ag.z = fmaf(wg4[i].z, h4.z, ag.z); ag.w = fmaf(wg4[i].w, h4.w, ag.w);
            ao.x = fmaf(wo4[i].x, h4.x, ao.x); ao.y = fmaf(wo4[i].y, h4.y, ao.y);
            ao.z = fmaf(wo4[i].z, h4.z, ao.z); ao.w = fmaf(wo4[i].w, h4.w, ao.w);
        }
        const float gi = xi + (ai.x + ai.y) + (ai.z + ai.w);
        const float gf = xf + (af.x + af.y) + (af.z + af.w);
        const float gg = xgg + (ag.x + ag.y) + (ag.z + ag.w);
        const float go = xo + (ao.x + ao.y) + (ao.z + ao.w);

        // prefetch next step's xg while the nonlinearity chain runs
        const int tn = t + step;
        if (s + 1 < T_) {
            xi = xg[(size_t)tn * GATES + r];
            xf = xg[(size_t)tn * GATES + HID + r];
            xgg = xg[(size_t)tn * GATES + 2 * HID + r];
            xo = xg[(size_t)tn * GATES + 3 * HID + r];
        }

        const float si = fsigmoid(gi);
        const float sf = fsigmoid(gf);
        const float so = fsigmoid(go);
        c = sf * c + si * ftanh(gg);
        const float h = so * ftanh(c);

        // DS pipe is in-order per wave: this write lands after the 16 reads
        // above. Wait for it before next iteration's reads.
        hs[r] = h;
        Xrow[t] = h;
        asm volatile("s_waitcnt lgkmcnt(0)" ::: "memory");
        t = tn;
    }
}

// ---------------------------------------------------------------------------
// K3: wave module. grid(ceil(T/256)=3, 128, 32), block 256
__global__ void wave_kernel(const float* __restrict__ X,
                            const float* __restrict__ bw, const float* __restrict__ bb,
                            float* __restrict__ wave) {
    const int b = blockIdx.z, c = blockIdx.y;
    const int t0 = blockIdx.x * 256;
    const int tid = threadIdx.x;
    __shared__ float xs[256 + 14];
    __shared__ float bws[NWAVE][16];
    __shared__ float bbs[NWAVE];
    const float* xrow = X + ((size_t)(b * CCH + c)) * T_;
    for (int i = tid; i < 270; i += 256) {
        int tt = t0 - 7 + i;
        xs[i] = (tt >= 0 && tt < T_) ? xrow[tt] : 0.f;
    }
    if (tid < NWAVE * 15) bws[tid / 15][tid % 15] = bw[tid];
    if (tid < NWAVE) bbs[tid] = bb[tid];
    __syncthreads();
    const int t = t0 + tid;
    if (t >= T_) return;
    float win[15];
#pragma unroll
    for (int k = 0; k < 15; ++k) win[k] = xs[tid + k];
    float e[8];
    e[0] = win[7];
#pragma unroll
    for (int m = 1; m < 8; ++m) e[m] = win[7 - m] + win[7 + m];
    const float c0 = 6.28318530717958647692f / 15.f;  // 2*pi/WIDE
#pragma unroll
    for (int ii = 0; ii < NWAVE; ++ii) {
        float sc = bbs[ii];
#pragma unroll
        for (int k = 0; k < 15; ++k) sc += win[k] * bws[ii][k];
        sc = fmaxf(sc, 0.f);
        const float phi = c0 * (float)(ii + 1) * sc;
        float o = e[0];
#pragma unroll
        for (int m = 1; m < 8; ++m) o += e[m] * __cosf(phi * (float)m);
        const float q = (truncf(sc * 15.f) + 1.f) * (2.f / 17.f);
        wave[((size_t)(b * WCH + ii * CCH + c)) * T_ + t] = o * rsqrtf(q);
    }
}

// ---------------------------------------------------------------------------
// Generic training-mode BN statistics: one block per channel
__global__ void bn_stats_kernel(const float* __restrict__ x, int Bn, int C, int L,
                                float* __restrict__ mean, float* __restrict__ rstd) {
    const int c = blockIdx.x;
    const int tid = threadIdx.x;
    float s = 0.f, s2 = 0.f;
    for (int b = 0; b < Bn; ++b) {
        const float* row = x + ((size_t)b * C + c) * L;
        for (int l = tid; l < L; l += 256) { float v = row[l]; s += v; s2 += v * v; }
    }
#pragma unroll
    for (int off = 32; off > 0; off >>= 1) { s += __shfl_down(s, off); s2 += __shfl_down(s2, off); }
    __shared__ float ss[4], ss2[4];
    if ((tid & 63) == 0) { ss[tid >> 6] = s; ss2[tid >> 6] = s2; }
    __syncthreads();
    if (tid == 0) {
        float S = ss[0] + ss[1] + ss[2] + ss[3];
        float S2 = ss2[0] + ss2[1] + ss2[2] + ss2[3];
        float n = (float)(Bn * L);
        float m = S / n;
        float v = S2 / n - m * m;
        mean[c] = m;
        rstd[c] = rsqrtf(v + 1e-5f);
    }
}

// In-place BN affine apply
__global__ void bn_apply_kernel(float* __restrict__ x, const float* __restrict__ mean,
                                const float* __restrict__ rstd, const float* __restrict__ g,
                                const float* __restrict__ be, int C, int L, int total) {
    int i = blockIdx.x * 256 + threadIdx.x;
    if (i >= total) return;
    int c = (i / L) % C;
    x[i] = (x[i] - mean[c]) * rstd[c] * g[c] + be[c];
}

// ---------------------------------------------------------------------------
// conv2: [32,768,518] -> relu -> [32,128,516], k=3. grid(3,16,32), block 256
__global__ void conv2_kernel(const float* __restrict__ in, const float* __restrict__ w,
                             const float* __restrict__ bias, float* __restrict__ out) {
    const int t = blockIdx.x * 256 + threadIdx.x;
    const int o0 = blockIdx.y * 8;
    const int b = blockIdx.z;
    if (t >= L2_) return;
    float acc[8];
#pragma unroll
    for (int j = 0; j < 8; ++j) acc[j] = bias[o0 + j];
    const float* inb = in + (size_t)b * WCH * T_ + t;
    const float* wb = w + (size_t)o0 * WCH * 3;
    for (int c = 0; c < WCH; ++c) {
        float x0 = inb[c * T_], x1 = inb[c * T_ + 1], x2 = inb[c * T_ + 2];
        const float* wc = wb + c * 3;
#pragma unroll
        for (int j = 0; j < 8; ++j) {
            const float* wj = wc + (size_t)j * WCH * 3;
            acc[j] += x0 * wj[0] + x1 * wj[1] + x2 * wj[2];
        }
    }
    const size_t ob = ((size_t)b * 128 + o0) * L2_ + t;
#pragma unroll
    for (int j = 0; j < 8; ++j) out[ob + (size_t)j * L2_] = fmaxf(acc[j], 0.f);
}

// conv3: [32,128,516] -> relu -> [32,32,512], k=5. grid(2,4,32), block 256
__global__ void conv3_kernel(const float* __restrict__ in, const float* __restrict__ w,
                             const float* __restrict__ bias, float* __restrict__ out) {
    const int t = blockIdx.x * 256 + threadIdx.x;
    const int o0 = blockIdx.y * 8;
    const int b = blockIdx.z;
    if (t >= L3_) return;
    float acc[8];
#pragma unroll
    for (int j = 0; j < 8; ++j) acc[j] = bias[o0 + j];
    const float* inb = in + (size_t)b * 128 * L2_ + t;
    const float* wb = w + (size_t)o0 * 128 * 5;
    for (int c = 0; c < 128; ++c) {
        float x0 = inb[c * L2_], x1 = inb[c * L2_ + 1], x2 = inb[c * L2_ + 2];
        float x3 = inb[c * L2_ + 3], x4 = inb[c * L2_ + 4];
        const float* wc = wb + c * 5;
#pragma unroll
        for (int j = 0; j < 8; ++j) {
            const float* wj = wc + (size_t)j * 128 * 5;
            acc[j] += x0 * wj[0] + x1 * wj[1] + x2 * wj[2] + x3 * wj[3] + x4 * wj[4];
        }
    }
    const size_t ob = ((size_t)b * 32 + o0) * L3_ + t;
#pragma unroll
    for (int j = 0; j < 8; ++j) out[ob + (size_t)j * L3_] = fmaxf(acc[j], 0.f);
}

// conv4: [32,32,512] -> relu -> [32,16,510], k=3. grid(2,16,32), block 256
__global__ void conv4_kernel(const float* __restrict__ in, const float* __restrict__ w,
                             const float* __restrict__ bias, float* __restrict__ out) {
    const int t = blockIdx.x * 256 + threadIdx.x;
    const int o = blockIdx.y;
    const int b = blockIdx.z;
    if (t >= L4_) return;
    float acc = bias[o];
    const float* inb = in + (size_t)b * 32 * L3_ + t;
    const float* wo = w + (size_t)o * 32 * 3;
    for (int c = 0; c < 32; ++c) {
        acc += inb[c * L3_] * wo[c * 3] + inb[c * L3_ + 1] * wo[c * 3 + 1] +
               inb[c * L3_ + 2] * wo[c * 3 + 2];
    }
    out[((size_t)b * 16 + o) * L4_ + t] = fmaxf(acc, 0.f);
}

// DWT branch: channel-mean then Haar cascade bands, upsampled. grid(32), block 512
__global__ void dwt_kernel(const float* __restrict__ y3, float* __restrict__ dwt) {
    const int b = blockIdx.x, l = threadIdx.x;  // l in [0,512)
    __shared__ float cm[L3_];
    float s = 0.f;
    for (int ch = 0; ch < 32; ++ch) s += y3[((size_t)b * 32 + ch) * L3_ + l];
    cm[l] = s * (1.f / 32.f);
    __syncthreads();
    const float s1 = 0.70710678118654752440f;
    const float s2 = 0.5f;
    const float s3 = 0.35355339059327378f;
    const float s4 = 0.25f;
    const int b16 = l & ~15, b8 = l & ~7, b4v = l & ~3, b2v = l & ~1;
    float sa = 0.f, sb = 0.f;
#pragma unroll
    for (int i = 0; i < 8; ++i) { sa += cm[b16 + i]; sb += cm[b16 + 8 + i]; }
    float a4 = (sa + sb) * s4;
    float d4 = (sa - sb) * s4;
    float ta = 0.f, tb = 0.f;
#pragma unroll
    for (int i = 0; i < 4; ++i) { ta += cm[b8 + i]; tb += cm[b8 + 4 + i]; }
    float d3 = (ta - tb) * s3;
    float d2 = (cm[b4v] + cm[b4v + 1] - cm[b4v + 2] - cm[b4v + 3]) * s2;
    float d1 = (cm[b2v] - cm[b2v + 1]) * s1;
    const size_t base = (size_t)b * 5 * L3_ + l;
    dwt[base] = a4;
    dwt[base + L3_] = d4;
    dwt[base + 2 * L3_] = d3;
    dwt[base + 3 * L3_] = d2;
    dwt[base + 4 * L3_] = d1;
}

// conv5: [32,5,512] -> relu -> [32,16,510], k=3. grid(2,16,32), block 256
__global__ void conv5_kernel(const float* __restrict__ in, const float* __restrict__ w,
                             const float* __restrict__ bias, float* __restrict__ out) {
    const int t = blockIdx.x * 256 + threadIdx.x;
    const int o = blockIdx.y;
    const int b = blockIdx.z;
    if (t >= L4_) return;
    float acc = bias[o];
    const float* inb = in + (size_t)b * 5 * L3_ + t;
    const float* wo = w + (size_t)o * 5 * 3;
#pragma unroll
    for (int c = 0; c < 5; ++c) {
        acc += inb[c * L3_] * wo[c * 3] + inb[c * L3_ + 1] * wo[c * 3 + 1] +
               inb[c * L3_ + 2] * wo[c * 3 + 2];
    }
    out[((size_t)b * 16 + o) * L4_ + t] = fmaxf(acc, 0.f);
}

// Final: fold BN4/BN5 into pooling (mean of affine = affine of mean), then FC.
// grid(32), block 256
__global__ void final_kernel(const float* __restrict__ y4, const float* __restrict__ y5,
                             const float* __restrict__ m4, const float* __restrict__ r4,
                             const float* __restrict__ g4, const float* __restrict__ be4,
                             const float* __restrict__ m5, const float* __restrict__ r5,
                             const float* __restrict__ g5, const float* __restrict__ be5,
                             const float* __restrict__ fcw, const float* __restrict__ fcb,
                             float* __restrict__ out) {
    const int b = blockIdx.x;
    const int tid = threadIdx.x;
    const int ch = tid >> 4, lane = tid & 15;
    float s4 = 0.f, s5 = 0.f;
    const float* p4 = y4 + ((size_t)b * 16 + ch) * L4_;
    const float* p5 = y5 + ((size_t)b * 16 + ch) * L4_;
    for (int l = lane; l < L4_; l += 16) { s4 += p4[l]; s5 += p5[l]; }
#pragma unroll
    for (int off = 8; off > 0; off >>= 1) { s4 += __shfl_down(s4, off); s5 += __shfl_down(s5, off); }
    __shared__ float shmean[16];
    if (lane == 0) {
        float mm4 = s4 / (float)L4_, mm5 = s5 / (float)L4_;
        float v4 = (mm4 - m4[ch]) * r4[ch] * g4[ch] + be4[ch];
        float v5 = (mm5 - m5[ch]) * r5[ch] * g5[ch] + be5[ch];
        shmean[ch] = 0.5f * (v4 + v5);
    }
    __syncthreads();
    if (tid < 10) {
        float a = fcb[tid];
#pragma unroll
        for (int c = 0; c < 16; ++c) a += shmean[c] * fcw[tid * 16 + c];
        out[b * 10 + tid] = a;
    }
}

// ---------------------------------------------------------------------------
extern "C" void kernel_launch(void* const* d_in, const int* in_sizes, int n_in,
                              void* d_out, int out_size, void* d_ws, size_t ws_size,
                              hipStream_t stream) {
    (void)in_sizes; (void)n_in; (void)out_size; (void)ws_size;
    const float* x   = (const float*)d_in[0];
    const float* wif = (const float*)d_in[1];
    const float* whf = (const float*)d_in[2];
    const float* bf  = (const float*)d_in[3];
    const float* wir = (const float*)d_in[4];
    const float* whr = (const float*)d_in[5];
    const float* br  = (const float*)d_in[6];
    const float* bw  = (const float*)d_in[7];
    const float* bb  = (const float*)d_in[8];
    const float* g1  = (const float*)d_in[9];  const float* be1 = (const float*)d_in[10];
    const float* g2  = (const float*)d_in[11]; const float* be2 = (const float*)d_in[12];
    const float* g3  = (const float*)d_in[13]; const float* be3 = (const float*)d_in[14];
    const float* g4  = (const float*)d_in[15]; const float* be4 = (const float*)d_in[16];
    const float* g5  = (const float*)d_in[17]; const float* be5 = (const float*)d_in[18];
    const float* w2  = (const float*)d_in[19]; const float* b2  = (const float*)d_in[20];
    const float* w3  = (const float*)d_in[21]; const float* b3  = (const float*)d_in[22];
    const float* w4  = (const float*)d_in[23]; const float* b4  = (const float*)d_in[24];
    const float* w5  = (const float*)d_in[25]; const float* b5  = (const float*)d_in[26];
    const float* fcw = (const float*)d_in[27]; const float* fcb = (const float*)d_in[28];
    float* out = (float*)d_out;
    float* ws  = (float*)d_ws;

    // Workspace layout (floats). xg region is reused by `wave` after the LSTM.
    float* xg_f = ws;                       //  4,243,456
    float* xg_r = ws + 4243456;             //  4,243,456
    float* wave = ws;                       // 12,730,368 (reuses xg region)
    float* X    = ws + 12730368;            //  2,121,728
    float* y2   = ws + 14852096;            //  2,113,536
    float* y3   = ws + 16965632;            //    524,288
    float* y4   = ws + 17489920;            //    261,120
    float* y5   = ws + 17751040;            //    261,120
    float* dwt  = ws + 18012160;            //     81,920
    float* m1 = ws + 18094080; float* r1 = m1 + 768;
    float* m2 = r1 + 768;      float* r2 = m2 + 128;
    float* m3 = r2 + 128;      float* r3 = m3 + 32;
    float* m4 = r3 + 32;       float* r4 = m4 + 16;
    float* m5 = r4 + 16;       float* r5 = m5 + 16;   // ends at 18,096,000 floats (~72.4 MB)

    // 1) input projections (both directions)
    xg_kernel<<<dim3(65, 32), 256, 0, stream>>>(x, wif, bf, wir, br, xg_f, xg_r);
    // 2) bidirectional LSTM recurrence -> X [32,128,518]  (one wave per chain)
    lstm_kernel<<<dim3(64), 64, 0, stream>>>(xg_f, xg_r, whf, whr, X);
    // 3) wave module -> wave [32,768,518]
    wave_kernel<<<dim3(3, CCH, B_), 256, 0, stream>>>(X, bw, bb, wave);
    // 4) BN1
    bn_stats_kernel<<<dim3(WCH), 256, 0, stream>>>(wave, B_, WCH, T_, m1, r1);
    bn_apply_kernel<<<dim3((B_ * WCH * T_ + 255) / 256), 256, 0, stream>>>(
        wave, m1, r1, g1, be1, WCH, T_, B_ * WCH * T_);
    // 5) conv2 + relu -> y2; BN2
    conv2_kernel<<<dim3(3, 16, B_), 256, 0, stream>>>(wave, w2, b2, y2);
    bn_stats_kernel<<<dim3(128), 256, 0, stream>>>(y2, B_, 128, L2_, m2, r2);
    bn_apply_kernel<<<dim3((B_ * 128 * L2_ + 255) / 256), 256, 0, stream>>>(
        y2, m2, r2, g2, be2, 128, L2_, B_ * 128 * L2_);
    // 6) conv3 + relu -> y3; BN3
    conv3_kernel<<<dim3(2, 4, B_), 256, 0, stream>>>(y2, w3, b3, y3);
    bn_stats_kernel<<<dim3(32), 256, 0, stream>>>(y3, B_, 32, L3_, m3, r3);
    bn_apply_kernel<<<dim3((B_ * 32 * L3_ + 255) / 256), 256, 0, stream>>>(
        y3, m3, r3, g3, be3, 32, L3_, B_ * 32 * L3_);
    // 7) conv4 + relu -> y4; BN4 stats only (apply folded into final)
    conv4_kernel<<<dim3(2, 16, B_), 256, 0, stream>>>(y3, w4, b4, y4);
    bn_stats_kernel<<<dim3(16), 256, 0, stream>>>(y4, B_, 16, L4_, m4, r4);
    // 8) DWT bands from y3 -> dwt [32,5,512]; conv5 + relu -> y5; BN5 stats
    dwt_kernel<<<dim3(B_), 512, 0, stream>>>(y3, dwt);
    conv5_kernel<<<dim3(2, 16, B_), 256, 0, stream>>>(dwt, w5, b5, y5);
    bn_stats_kernel<<<dim3(16), 256, 0, stream>>>(y5, B_, 16, L4_, m5, r5);
    // 9) pool (+BN4/BN5 affine) + FC -> out [32,10]
    final_kernel<<<dim3(B_), 256, 0, stream>>>(y4, y5, m4, r4, g4, be4, m5, r5, g5, be5,
                                               fcw, fcb, out);
}